// Round 6
// baseline (179.404 us; speedup 1.0000x reference)
//
#include <hip/hip_runtime.h>

// QMixer — round 6: barrier-free gemm2.
// Phase0/gemm1/epi identical to round 5 (replay-proven). gemm2 rebuilt:
//   waves = 2(row-half) x 2(agent-half) x 2(e-half); A-frags in registers,
//   B read directly from L2 (static dbuf bdA/bdB, 1-batch-ahead prefetch),
//   NO per-agent barriers (was 32 full-CU drains), no LDS B staging.
//   Agent-half partials reduced once through a 33 KB f32 LDS buffer.
// Barriers total: 5.

#define SDIM 512
#define HD   256
#define EDIM 64
#define NAG  32

typedef short short8v __attribute__((ext_vector_type(8)));
typedef short short4v __attribute__((ext_vector_type(4)));
typedef float f32x4  __attribute__((ext_vector_type(4)));

__device__ __forceinline__ unsigned short f2bf(float f) {
  unsigned int u = __float_as_uint(f);
  unsigned int r = (u + 0x7FFFu + ((u >> 16) & 1u)) >> 16;
  return (unsigned short)r;
}

__device__ __forceinline__ short4v cvt4(float4 a) {
  short4v r;
  r[0] = (short)f2bf(a.x); r[1] = (short)f2bf(a.y);
  r[2] = (short)f2bf(a.z); r[3] = (short)f2bf(a.w);
  return r;
}

// ---------------- convert weights to bf16 ----------------
// W0cat [640][512] = w1_0(256) | wf_0(256) | hb_w(64) | v0_w(64)
// w12b [2048][256]; wf2b [64][256]
__global__ void qmix_convert(const float* __restrict__ w1_0, const float* __restrict__ wf_0,
                             const float* __restrict__ hb_w, const float* __restrict__ v0_w,
                             const float* __restrict__ w1_2, const float* __restrict__ wf_2,
                             unsigned short* __restrict__ W0cat, unsigned short* __restrict__ w12b,
                             unsigned short* __restrict__ wf2b) {
  int i = blockIdx.x * 256 + threadIdx.x;
  if (i < 327680) {
    float v;
    if (i < 131072)      v = w1_0[i];
    else if (i < 262144) v = wf_0[i - 131072];
    else if (i < 294912) v = hb_w[i - 262144];
    else                 v = v0_w[i - 294912];
    W0cat[i] = f2bf(v);
  } else if (i < 851968) {
    w12b[i - 327680] = f2bf(w1_2[i - 327680]);
  } else if (i < 868352) {
    wf2b[i - 851968] = f2bf(wf_2[i - 851968]);
  }
}

// ---------------- fused main kernel ----------------
__global__ __launch_bounds__(512, 2) void qmix_main(
    const float* __restrict__ agent_qs, const float* __restrict__ states,
    const unsigned short* __restrict__ W0cat, const unsigned short* __restrict__ w12b,
    const unsigned short* __restrict__ wf2b,
    const float* __restrict__ b1_0, const float* __restrict__ bf_0,
    const float* __restrict__ hb_b, const float* __restrict__ v0_b,
    const float* __restrict__ v2_w, const float* __restrict__ b1_2,
    const float* __restrict__ bf_2, const float* __restrict__ v2_b,
    float* __restrict__ out)
{
  __shared__ unsigned short sA[64 * 512];      // 64 KB: states, then h1|hf (swizzled)
  __shared__ float pbuf[2][64 * 65];           // 33.3 KB: gemm2 agent-half partials
  __shared__ float b1t[64 * 65];               // 16.6 KB
  __shared__ float q_lds[64 * 33];             // 8.4 KB
  __shared__ float vrow[64];
  __shared__ float ypart[4][64];               // 1 KB

  const int t    = threadIdx.x;
  const int r0   = blockIdx.x * 64;
  const int wave = t >> 6, lane = t & 63;
  const int lrow = lane & 15, lk = lane >> 4;

  // ---- phase 0: issue ALL global loads up front ----
  const float4* gS4 = (const float4*)(states + (size_t)r0 * SDIM);
  float4 L[16];
#pragma unroll
  for (int it = 0; it < 16; it++) L[it] = gS4[it * 512 + t];
  float4 qreg = ((const float4*)(agent_qs + (size_t)r0 * NAG))[t];

  // gemm1 B prefetch for ks=0,1 (L2-resident weights)
  const int colbase = wave * 80;
  const unsigned short* bp[5];
#pragma unroll
  for (int f = 0; f < 5; f++)
    bp[f] = W0cat + (size_t)(colbase + f * 16 + lrow) * SDIM + 8 * lk;
  short8v bregs[2][5];
#pragma unroll
  for (int f = 0; f < 5; f++) bregs[0][f] = *(const short8v*)(bp[f]);
#pragma unroll
  for (int f = 0; f < 5; f++) bregs[1][f] = *(const short8v*)(bp[f] + 32);

  // write FULL states tile + q tile, then one barrier
#pragma unroll
  for (int it = 0; it < 16; it++) {
    int idx = it * 512 + t;
    int row = idx >> 7, c4 = idx & 127;
    int byte = (row * 1024 + c4 * 8) ^ ((row & 7) << 4);
    *(short4v*)((char*)sA + byte) = cvt4(L[it]);
  }
  {
    int qrow = t >> 3, qc = (t & 7) * 4;
    q_lds[qrow * 33 + qc + 0] = qreg.x;
    q_lds[qrow * 33 + qc + 1] = qreg.y;
    q_lds[qrow * 33 + qc + 2] = qreg.z;
    q_lds[qrow * 33 + qc + 3] = qreg.w;
  }
  __syncthreads();   // bar1

  // ---- gemm1: acc[4][5], wave tile 64 rows x 80 cols ----
  f32x4 acc[4][5];
#pragma unroll
  for (int i = 0; i < 4; i++)
#pragma unroll
    for (int f = 0; f < 5; f++) acc[i][f] = (f32x4){0.f, 0.f, 0.f, 0.f};

#pragma unroll
  for (int ks = 0; ks < 16; ks++) {
    const int p = ks & 1;
    short8v af[4];
#pragma unroll
    for (int i = 0; i < 4; i++) {
      int row = i * 16 + lrow;
      int byte = (row * 1024 + ks * 64 + lk * 16) ^ ((row & 7) << 4);
      af[i] = *(const short8v*)((const char*)sA + byte);
    }
#pragma unroll
    for (int f = 0; f < 5; f++)
#pragma unroll
      for (int i = 0; i < 4; i++)
        acc[i][f] = __builtin_amdgcn_mfma_f32_16x16x32_bf16(af[i], bregs[p][f], acc[i][f], 0, 0, 0);
    if (ks < 14) {
#pragma unroll
      for (int f = 0; f < 5; f++) bregs[p][f] = *(const short8v*)(bp[f] + (ks + 2) * 32);
    }
  }

  __syncthreads();   // bar2: all sA reads done; safe to overwrite with h-tile

  // ---- gemm1 epilogue: heads by column range, h written back into sA ----
  {
    float vs[4][4];
#pragma unroll
    for (int i = 0; i < 4; i++)
#pragma unroll
      for (int rr = 0; rr < 4; rr++) vs[i][rr] = 0.f;

#pragma unroll
    for (int f = 0; f < 5; f++) {
      int cb  = colbase + f * 16;    // wave-uniform
      int col = cb + lrow;
      if (cb < 512) {
        float bv = (cb < 256) ? b1_0[col] : bf_0[col - 256];
#pragma unroll
        for (int i = 0; i < 4; i++)
#pragma unroll
          for (int rr = 0; rr < 4; rr++) {
            int row = i * 16 + lk * 4 + rr;
            float v = fmaxf(acc[i][f][rr] + bv, 0.f);
            int byte = (row * 1024 + col * 2) ^ ((row & 7) << 4);
            *(unsigned short*)((char*)sA + byte) = f2bf(v);
          }
      } else if (cb < 576) {
        int e = col - 512;
        float bv = hb_b[e];
#pragma unroll
        for (int i = 0; i < 4; i++)
#pragma unroll
          for (int rr = 0; rr < 4; rr++) {
            int row = i * 16 + lk * 4 + rr;
            b1t[row * 65 + e] = acc[i][f][rr] + bv;
          }
      } else {
        int e = col - 576;
        float bv = v0_b[e], wv = v2_w[e];
#pragma unroll
        for (int i = 0; i < 4; i++)
#pragma unroll
          for (int rr = 0; rr < 4; rr++)
            vs[i][rr] = fmaf(fmaxf(acc[i][f][rr] + bv, 0.f), wv, vs[i][rr]);
      }
    }
    if (colbase == 560) {    // wave 7 owns the v head
#pragma unroll
      for (int i = 0; i < 4; i++)
#pragma unroll
        for (int rr = 0; rr < 4; rr++) {
          float v = vs[i][rr];
#pragma unroll
          for (int m = 1; m < 16; m <<= 1) v += __shfl_xor(v, m, 64);
          if (lrow == 0) vrow[i * 16 + lk * 4 + rr] = v;
        }
    }
  }

  // ---- gemm2 wave roles ----
  const int wr = wave >> 2;        // 0..1 rows-half
  const int g  = (wave >> 1) & 1;  // 0..1 agents-half
  const int wc = wave & 1;         // 0..1 e-half

  // prefetch first B batch (agent g*16, jb=0) — global loads, pre-barrier
  short8v bdA[8], bdB[8];
  {
    const unsigned short* src = w12b + ((size_t)((g * 16) * EDIM + wc * 32 + lrow)) * HD + 8 * lk;
#pragma unroll
    for (int kf = 0; kf < 8; kf++) bdA[kf] = *(const short8v*)(src + kf * 32);
  }

  __syncthreads();   // bar3: h-tile, b1t, vrow visible

  // hoist A fragments (h1, rows-half wr, K=256) into registers
  short8v afr[2][8];
#pragma unroll
  for (int i = 0; i < 2; i++) {
    int row = wr * 32 + i * 16 + lrow;
#pragma unroll
    for (int kf = 0; kf < 8; kf++) {
      int byte = (row * 1024 + kf * 64 + lk * 16) ^ ((row & 7) << 4);
      afr[i][kf] = *(const short8v*)((const char*)sA + byte);
    }
  }

  f32x4 hac[2][2];   // [row-frag i][e-frag jb]
#pragma unroll
  for (int i = 0; i < 2; i++)
#pragma unroll
    for (int jb = 0; jb < 2; jb++) hac[i][jb] = (f32x4){0.f, 0.f, 0.f, 0.f};

#pragma unroll 1
  for (int s2 = 0; s2 < 16; s2++) {
    const int a = g * 16 + s2;

    // prefetch (a, jb=1) into bdB
    {
      const unsigned short* src = w12b + ((size_t)(a * EDIM + wc * 32 + 16 + lrow)) * HD + 8 * lk;
#pragma unroll
      for (int kf = 0; kf < 8; kf++) bdB[kf] = *(const short8v*)(src + kf * 32);
    }
    // compute jb=0 from bdA
    {
      f32x4 T[2];
      T[0] = (f32x4){0.f, 0.f, 0.f, 0.f};
      T[1] = (f32x4){0.f, 0.f, 0.f, 0.f};
#pragma unroll
      for (int kf = 0; kf < 8; kf++)
#pragma unroll
        for (int i = 0; i < 2; i++)
          T[i] = __builtin_amdgcn_mfma_f32_16x16x32_bf16(afr[i][kf], bdA[kf], T[i], 0, 0, 0);
      float bbias = b1_2[a * EDIM + wc * 32 + lrow];
#pragma unroll
      for (int i = 0; i < 2; i++)
#pragma unroll
        for (int r = 0; r < 4; r++) {
          float qv = q_lds[(wr * 32 + i * 16 + lk * 4 + r) * 33 + a];
          hac[i][0][r] = fmaf(qv, fabsf(T[i][r] + bbias), hac[i][0][r]);
        }
    }
    // prefetch (a+1, jb=0) into bdA
    if (s2 < 15) {
      const unsigned short* src = w12b + ((size_t)((a + 1) * EDIM + wc * 32 + lrow)) * HD + 8 * lk;
#pragma unroll
      for (int kf = 0; kf < 8; kf++) bdA[kf] = *(const short8v*)(src + kf * 32);
    }
    // compute jb=1 from bdB
    {
      f32x4 T[2];
      T[0] = (f32x4){0.f, 0.f, 0.f, 0.f};
      T[1] = (f32x4){0.f, 0.f, 0.f, 0.f};
#pragma unroll
      for (int kf = 0; kf < 8; kf++)
#pragma unroll
        for (int i = 0; i < 2; i++)
          T[i] = __builtin_amdgcn_mfma_f32_16x16x32_bf16(afr[i][kf], bdB[kf], T[i], 0, 0, 0);
      float bbias = b1_2[a * EDIM + wc * 32 + 16 + lrow];
#pragma unroll
      for (int i = 0; i < 2; i++)
#pragma unroll
        for (int r = 0; r < 4; r++) {
          float qv = q_lds[(wr * 32 + i * 16 + lk * 4 + r) * 33 + a];
          hac[i][1][r] = fmaf(qv, fabsf(T[i][r] + bbias), hac[i][1][r]);
        }
    }
  }

  // ---- write agent-half partials ----
#pragma unroll
  for (int i = 0; i < 2; i++)
#pragma unroll
    for (int jb = 0; jb < 2; jb++)
#pragma unroll
      for (int r = 0; r < 4; r++) {
        int row = wr * 32 + i * 16 + lk * 4 + r;
        int e   = wc * 32 + jb * 16 + lrow;
        pbuf[g][row * 65 + e] = hac[i][jb][r];
      }

  // ---- wf B loads (global, issued before the barrier) ----
  const int eq = wave & 3;         // epilogue e-quarter
  short8v bwf[8];
#pragma unroll
  for (int kf = 0; kf < 8; kf++)
    bwf[kf] = *(const short8v*)(wf2b + (size_t)(eq * 16 + lrow) * HD + kf * 32 + 8 * lk);

  __syncthreads();   // bar4: pbuf visible

  // ---- wf: |hf @ wf_2^T + bf_2| for (rows-half wr, e-quarter eq) ----
  f32x4 wfa[2];
  wfa[0] = (f32x4){0.f, 0.f, 0.f, 0.f};
  wfa[1] = (f32x4){0.f, 0.f, 0.f, 0.f};
#pragma unroll
  for (int i = 0; i < 2; i++) {
    int row = wr * 32 + i * 16 + lrow;
#pragma unroll
    for (int kf = 0; kf < 8; kf++) {
      int byte = (row * 1024 + 512 + kf * 64 + lk * 16) ^ ((row & 7) << 4);
      short8v af2 = *(const short8v*)((const char*)sA + byte);
      wfa[i] = __builtin_amdgcn_mfma_f32_16x16x32_bf16(af2, bwf[kf], wfa[i], 0, 0, 0);
    }
  }

  // ---- final epilogue: elu(hid+b1)*wfin, reduce over e-quarter ----
  {
    float ys[2][4];
#pragma unroll
    for (int i = 0; i < 2; i++)
#pragma unroll
      for (int r = 0; r < 4; r++) {
        int row = wr * 32 + i * 16 + lk * 4 + r;
        int e   = eq * 16 + lrow;
        float hid = pbuf[0][row * 65 + e] + pbuf[1][row * 65 + e];
        float pre = hid + b1t[row * 65 + e];
        float h = pre > 0.f ? pre : expm1f(pre);
        float wfv = fabsf(wfa[i][r] + bf_2[e]);
        ys[i][r] = h * wfv;
      }
#pragma unroll
    for (int m = 1; m < 16; m <<= 1)
#pragma unroll
      for (int i = 0; i < 2; i++)
#pragma unroll
        for (int r = 0; r < 4; r++) ys[i][r] += __shfl_xor(ys[i][r], m, 64);
    if (lrow == 0) {
#pragma unroll
      for (int i = 0; i < 2; i++)
#pragma unroll
        for (int r = 0; r < 4; r++)
          ypart[eq][wr * 32 + i * 16 + lk * 4 + r] = ys[i][r];
    }
  }
  __syncthreads();   // bar5
  if (t < 64) {
    out[r0 + t] = ypart[0][t] + ypart[1][t] + ypart[2][t] + ypart[3][t]
                + vrow[t] + v2_b[0];
  }
}

extern "C" void kernel_launch(void* const* d_in, const int* in_sizes, int n_in,
                              void* d_out, int out_size, void* d_ws, size_t ws_size,
                              hipStream_t stream) {
  const float* agent_qs = (const float*)d_in[0];
  const float* states   = (const float*)d_in[1];
  const float* w1_0 = (const float*)d_in[2];
  const float* b1_0 = (const float*)d_in[3];
  const float* w1_2 = (const float*)d_in[4];
  const float* b1_2 = (const float*)d_in[5];
  const float* wf_0 = (const float*)d_in[6];
  const float* bf_0 = (const float*)d_in[7];
  const float* wf_2 = (const float*)d_in[8];
  const float* bf_2 = (const float*)d_in[9];
  const float* hb_w = (const float*)d_in[10];
  const float* hb_b = (const float*)d_in[11];
  const float* v0_w = (const float*)d_in[12];
  const float* v0_b = (const float*)d_in[13];
  const float* v2_w = (const float*)d_in[14];
  const float* v2_b = (const float*)d_in[15];

  char* ws = (char*)d_ws;
  unsigned short* W0cat = (unsigned short*)ws;                 //   655,360 B
  unsigned short* w12b  = (unsigned short*)(ws + 655360);      // 1,048,576 B
  unsigned short* wf2b  = (unsigned short*)(ws + 1703936);     //    32,768 B

  qmix_convert<<<3392, 256, 0, stream>>>(w1_0, wf_0, hb_w, v0_w, w1_2, wf_2,
                                         W0cat, w12b, wf2b);
  qmix_main<<<512, 512, 0, stream>>>(agent_qs, states, W0cat, w12b, wf2b,
                                     b1_0, bf_0, hb_b, v0_b, v2_w, b1_2, bf_2, v2_b,
                                     (float*)d_out);
}